// Round 8
// baseline (472.097 us; speedup 1.0000x reference)
//
#include <hip/hip_runtime.h>
#include <cstdint>

typedef _Float16 f16;
typedef uint32_t u32;
typedef f16 f16x2 __attribute__((ext_vector_type(2)));
typedef f16 f16x8 __attribute__((ext_vector_type(8)));
typedef float f32x4 __attribute__((ext_vector_type(4)));
typedef float f32x16 __attribute__((ext_vector_type(16)));
typedef u32 u32x4 __attribute__((ext_vector_type(4)));

#define NROWS 32768   // B*S = 8*4096
#define D_IN 1024
#define M_DIM 512
#define NKEYS 4096
#define KTOP 8

__device__ __forceinline__ u32 umax32(u32 a, u32 b) { return a > b ? a : b; }
__device__ __forceinline__ u32 umin32(u32 a, u32 b) { return a < b ? a : b; }

// async global->LDS, 16B per lane. LDS dest is wave-uniform base + lane*16 (HW).
__device__ __forceinline__ void gload_lds16(const void* src, void* dst) {
  __builtin_amdgcn_global_load_lds(
      (const __attribute__((address_space(1))) uint32_t*)src,
      (__attribute__((address_space(3))) uint32_t*)dst, 16, 0, 0);
}

// ---------------------------------------------------------------------------
// prep: fp32->fp16 conversions + weight transposes (LDS-tiled, coalesced)
// ---------------------------------------------------------------------------
__global__ void prep_kernel(const float* __restrict__ keys, const float* __restrict__ values,
                            const float* __restrict__ wq, const float* __restrict__ wo,
                            f16* __restrict__ keys_h, f16* __restrict__ values_h,
                            f16* __restrict__ wqT, f16* __restrict__ woT) {
  const int b = blockIdx.x, t = threadIdx.x;
  if (b < 2048) {
    const float* src = (b < 1024) ? keys : values;
    f16* dst = (b < 1024) ? keys_h : values_h;
    const int bb = b & 1023;
    const size_t base = (size_t)bb * 2048 + (size_t)t * 8;
    f32x4 a = *(const f32x4*)(src + base);
    f32x4 c2 = *(const f32x4*)(src + base + 4);
    f16x8 o;
    o[0] = (f16)a[0]; o[1] = (f16)a[1]; o[2] = (f16)a[2]; o[3] = (f16)a[3];
    o[4] = (f16)c2[0]; o[5] = (f16)c2[1]; o[6] = (f16)c2[2]; o[7] = (f16)c2[3];
    *(f16x8*)(dst + base) = o;
    return;
  }
  __shared__ float lds[64][65];
  if (b < 2176) {
    // wq: [1024 d][512 m] -> wqT [512 m][1024 d]
    const int tb = b - 2048;           // 0..127
    const int td = tb >> 3, tm = tb & 7;
#pragma unroll
    for (int p = 0; p < 16; ++p) {
      const int d_loc = p * 4 + (t >> 6), m_loc = t & 63;
      lds[d_loc][m_loc] = wq[(size_t)(td * 64 + d_loc) * 512 + tm * 64 + m_loc];
    }
    __syncthreads();
#pragma unroll
    for (int p = 0; p < 16; ++p) {
      const int m_loc = p * 4 + (t >> 6), d_loc = t & 63;
      wqT[(size_t)(tm * 64 + m_loc) * 1024 + td * 64 + d_loc] = (f16)lds[d_loc][m_loc];
    }
  } else {
    // wo: [512 m][1024 od] -> woT [1024 od][512 m]
    const int tb = b - 2176;           // 0..127
    const int tmm = tb >> 4, tod = tb & 15;
#pragma unroll
    for (int p = 0; p < 16; ++p) {
      const int m_loc = p * 4 + (t >> 6), od_loc = t & 63;
      lds[m_loc][od_loc] = wo[(size_t)(tmm * 64 + m_loc) * 1024 + tod * 64 + od_loc];
    }
    __syncthreads();
#pragma unroll
    for (int p = 0; p < 16; ++p) {
      const int od_loc = p * 4 + (t >> 6), m_loc = t & 63;
      woT[(size_t)(tod * 64 + od_loc) * 512 + tmm * 64 + m_loc] = (f16)lds[m_loc][od_loc];
    }
  }
}

// ---------------------------------------------------------------------------
// qproj (r2 version, proven): row-major LDS + XOR swizzle, coalesced staging.
// ---------------------------------------------------------------------------
__global__ __launch_bounds__(256, 2) void qproj_kernel(
    const float* __restrict__ query, const f16* __restrict__ wqT,
    const float* __restrict__ bq, f16* __restrict__ q_out) {
  __shared__ f16 Atile[32 * 1024];   // 64 KB
  const int tid = threadIdx.x;
  const int wave = tid >> 6, lane = tid & 63;
  const int g = lane >> 4, c = lane & 15;
  const int rowbase = blockIdx.x * 64 + wave * 16;
  const int row = rowbase + c;

  f16x8 Breg[32];
  {
    const float* qrow = query + (size_t)row * D_IN;
#pragma unroll
    for (int kk = 0; kk < 32; ++kk) {
      f32x4 lo = *(const f32x4*)(qrow + kk * 32 + g * 8);
      f32x4 hi = *(const f32x4*)(qrow + kk * 32 + g * 8 + 4);
      f16x8 v;
      v[0] = (f16)lo[0]; v[1] = (f16)lo[1]; v[2] = (f16)lo[2]; v[3] = (f16)lo[3];
      v[4] = (f16)hi[0]; v[5] = (f16)hi[1]; v[6] = (f16)hi[2]; v[7] = (f16)hi[3];
      Breg[kk] = v;
    }
  }

  for (int mt = 0; mt < 16; ++mt) {
    __syncthreads();
#pragma unroll
    for (int i2 = 0; i2 < 8; ++i2) {
      const int kr = wave * 8 + i2;
#pragma unroll
      for (int hb = 0; hb < 2; ++hb) {
        const u32 slot = (u32)(hb * 1024 + lane * 16);
        const u32 kb = slot ^ (u32)((kr & 7) << 4);
        const char* src = (const char*)(wqT + (size_t)(mt * 32 + kr) * D_IN) + kb;
        gload_lds16(src, (char*)Atile + kr * 2048 + hb * 1024);
      }
    }
    asm volatile("s_waitcnt vmcnt(0)" ::: "memory");
    __syncthreads();

    f32x4 acc0 = {0.f, 0.f, 0.f, 0.f};
    f32x4 acc1 = {0.f, 0.f, 0.f, 0.f};
#pragma unroll
    for (int kk = 0; kk < 32; ++kk) {
      const u32 base = (u32)(kk * 64 + g * 16);
      {
        const int ml = c;
        const u32 off = (u32)(ml * 2048) + (base ^ (u32)((ml & 7) << 4));
        f16x8 a = *(const f16x8*)((const char*)Atile + off);
        acc0 = __builtin_amdgcn_mfma_f32_16x16x32_f16(a, Breg[kk], acc0, 0, 0, 0);
      }
      {
        const int ml = 16 + c;
        const u32 off = (u32)(ml * 2048) + (base ^ (u32)((ml & 7) << 4));
        f16x8 a = *(const f16x8*)((const char*)Atile + off);
        acc1 = __builtin_amdgcn_mfma_f32_16x16x32_f16(a, Breg[kk], acc1, 0, 0, 0);
      }
    }

    f32x4 bq0 = *(const f32x4*)(bq + mt * 32 + g * 4);
    f32x4 bq1 = *(const f32x4*)(bq + mt * 32 + 16 + g * 4);
    f16* qp = q_out + (size_t)row * M_DIM + mt * 32 + g * 4;
    f16x2 p;
    p[0] = (f16)(acc0[0] + bq0[0]); p[1] = (f16)(acc0[1] + bq0[1]); *(f16x2*)(qp + 0) = p;
    p[0] = (f16)(acc0[2] + bq0[2]); p[1] = (f16)(acc0[3] + bq0[3]); *(f16x2*)(qp + 2) = p;
    p[0] = (f16)(acc1[0] + bq1[0]); p[1] = (f16)(acc1[1] + bq1[1]); *(f16x2*)(qp + 16) = p;
    p[0] = (f16)(acc1[2] + bq1[2]); p[1] = (f16)(acc1[3] + bq1[3]); *(f16x2*)(qp + 18) = p;
  }
}

// ---------------------------------------------------------------------------
// scores+topk, K-SPLIT wave pairs. 512-thread blocks (4 pairs x 32 rows =
// 128 rows) over a key half (2048). 32x32x16 MFMA; wave kpar owns dims
// [kpar*256, +256) -> Breg=64 VGPR -> 4 waves/SIMD. Fragment-major Ktile
// (32 slices x 1KB per tile, slice s = 32 keys x dims [s*16,+16), slot
// lane*16 = A-frag for key=lane&31, dims +8*(lane>>5)): conflict-free,
// imm-offset reads. Per tile: 16 MFMAs -> pair exchanges 8 f32 partials
// via LDS (b128 lane-linear) -> each wave finalizes+topk 8 scores.
// ---------------------------------------------------------------------------
__global__ __launch_bounds__(512, 4) void scores_topk_kernel(
    const f16* __restrict__ q, const f16* __restrict__ keys_h,
    u32* __restrict__ cand) {
  __shared__ f16 Ktile[2 * 32 * 512];       // 64 KB: 2 buf x 32 slices x 1KB
  __shared__ float xchg[4 * 2 * 2 * 256];   // 16 KB: [pair][who][r2][lane*4]
  const int tid = threadIdx.x;
  const int wave = tid >> 6, lane = tid & 63;
  const int h = lane >> 5, r32 = lane & 31;
  const int pair = wave >> 1, kpar = wave & 1;
  const int rb = blockIdx.x >> 1, half = blockIdx.x & 1;
  const int rowbase = rb * 128 + pair * 32;
  const int myrow = rowbase + r32;
  const int keybase = half * 2048;

  f16x8 Breg[16];
  {
    const f16* qr = q + (size_t)myrow * M_DIM + kpar * 256;
#pragma unroll
    for (int kk = 0; kk < 16; ++kk)
      Breg[kk] = *(const f16x8*)(qr + kk * 16 + h * 8);
  }

  u32 topE[KTOP], topO[KTOP];
#pragma unroll
  for (int j = 0; j < KTOP; ++j) { topE[j] = 0u; topO[j] = 0u; }

  // staging: wave stages slices [wave*4, +4); lane sources its own A-frag slot
  const int laneoff = r32 * M_DIM + h * 8;
  auto stage = [&](int buf, int kt) {
    const f16* tsrc = keys_h + (size_t)(keybase + kt * 32) * M_DIM + laneoff;
    char* dbase = (char*)Ktile + buf * 32768 + wave * 4096;
#pragma unroll
    for (int i2 = 0; i2 < 4; ++i2) {
      const int s = wave * 4 + i2;
      gload_lds16(tsrc + s * 16, dbase + i2 * 1024);
    }
  };

  float* xbase = xchg + pair * 1024;
  const char* base_rd = (const char*)Ktile + kpar * 16384 + lane * 16;

  stage(0, 0);
  asm volatile("s_waitcnt vmcnt(0)" ::: "memory");
  __syncthreads();

  for (int kt = 0; kt < 64; ++kt) {
    const int cur = kt & 1;
    if (kt < 63) stage(cur ^ 1, kt + 1);

    f32x16 acc;
#pragma unroll
    for (int i = 0; i < 16; ++i) acc[i] = 0.f;
    const char* tb = base_rd + cur * 32768;
    __builtin_amdgcn_s_setprio(1);
#pragma unroll
    for (int kk = 0; kk < 16; ++kk) {
      f16x8 fA = *(const f16x8*)(tb + kk * 1024);
      acc = __builtin_amdgcn_mfma_f32_32x32x16_f16(fA, Breg[kk], acc, 0, 0, 0);
    }
    __builtin_amdgcn_s_setprio(0);

    // send the half I don't finalize (static indices — rule #20)
    if (kpar == 0) {
      f32x4 w0 = {acc[8], acc[9], acc[10], acc[11]};
      f32x4 w1 = {acc[12], acc[13], acc[14], acc[15]};
      float* wp = xbase + lane * 4;
      *(f32x4*)(wp) = w0; *(f32x4*)(wp + 256) = w1;
    } else {
      f32x4 w0 = {acc[0], acc[1], acc[2], acc[3]};
      f32x4 w1 = {acc[4], acc[5], acc[6], acc[7]};
      float* wp = xbase + 512 + lane * 4;
      *(f32x4*)(wp) = w0; *(f32x4*)(wp + 256) = w1;
    }
    asm volatile("s_waitcnt vmcnt(0)" ::: "memory");
    __syncthreads();                      // stage(t+1) landed + xchg visible

    {
      const float* rp = xbase + (kpar ^ 1) * 512 + lane * 4;
      f32x4 p0 = *(const f32x4*)(rp);
      f32x4 p1 = *(const f32x4*)(rp + 256);
      float s8[8];
      if (kpar == 0) {
        s8[0] = acc[0] + p0[0]; s8[1] = acc[1] + p0[1];
        s8[2] = acc[2] + p0[2]; s8[3] = acc[3] + p0[3];
        s8[4] = acc[4] + p1[0]; s8[5] = acc[5] + p1[1];
        s8[6] = acc[6] + p1[2]; s8[7] = acc[7] + p1[3];
      } else {
        s8[0] = acc[8] + p0[0];  s8[1] = acc[9] + p0[1];
        s8[2] = acc[10] + p0[2]; s8[3] = acc[11] + p0[3];
        s8[4] = acc[12] + p1[0]; s8[5] = acc[13] + p1[1];
        s8[6] = acc[14] + p1[2]; s8[7] = acc[15] + p1[3];
      }
#pragma unroll
      for (int i = 0; i < 8; ++i) {
        const int reg = kpar * 8 + i;
        const u32 kidx = (u32)(keybase + kt * 32 + (reg & 3) + 8 * (reg >> 2) + 4 * h);
        const int bi = __float_as_int(s8[i]);
        const u32 mono = (u32)bi ^ (u32)((bi >> 31) | 0x80000000);   // order-preserving
        u32 x = ((mono + 0x800u) & 0xFFFFF000u) | kidx;              // 20b score + 12b idx
        if ((i & 1) == 0) {
#pragma unroll
          for (int j = 0; j < KTOP; ++j) { const u32 nt = umax32(topE[j], x); x = umin32(topE[j], x); topE[j] = nt; }
        } else {
#pragma unroll
          for (int j = 0; j < KTOP; ++j) { const u32 nt = umax32(topO[j], x); x = umin32(topO[j], x); topO[j] = nt; }
        }
      }
    }
    __syncthreads();                      // xchg reusable, buffer swap safe
  }

  // E/O merge (lane-exact over its covered keys)
#pragma unroll
  for (int j = 0; j < KTOP; ++j) {
    u32 x = topO[j];
#pragma unroll
    for (int jj = 0; jj < KTOP; ++jj) { const u32 nt = umax32(topE[jj], x); x = umin32(topE[jj], x); topE[jj] = nt; }
  }
  // h-merge (lane^32: same q-row, complementary keys)
  {
    u32 oth[KTOP];
#pragma unroll
    for (int j = 0; j < KTOP; ++j) oth[j] = (u32)__shfl((int)topE[j], lane ^ 32);
#pragma unroll
    for (int j = 0; j < KTOP; ++j) {
      u32 x = oth[j];
#pragma unroll
      for (int jj = 0; jj < KTOP; ++jj) { const u32 nt = umax32(topE[jj], x); x = umin32(topE[jj], x); topE[jj] = nt; }
    }
  }
  // pair merge via LDS (kpar=0 covers keys 0-15/32, kpar=1 covers 16-31/32)
  u32* xm = (u32*)xchg + pair * 512;
  if (kpar == 1) {
#pragma unroll
    for (int j = 0; j < KTOP; ++j) xm[j * 64 + lane] = topE[j];
  }
  __syncthreads();
  if (kpar == 0) {
#pragma unroll
    for (int j = 0; j < KTOP; ++j) {
      u32 x = xm[j * 64 + lane];
#pragma unroll
      for (int jj = 0; jj < KTOP; ++jj) { const u32 nt = umax32(topE[jj], x); x = umin32(topE[jj], x); topE[jj] = nt; }
    }
    if (h == 0) {
      u32* cp = cand + (size_t)myrow * 16 + half * 8;
      u32x4 a, b;
      a.x = topE[0]; a.y = topE[1]; a.z = topE[2]; a.w = topE[3];
      b.x = topE[4]; b.y = topE[5]; b.z = topE[6]; b.w = topE[7];
      *(u32x4*)(cp) = a;
      *(u32x4*)(cp + 4) = b;
    }
  }
}

// ---------------------------------------------------------------------------
// merge halves + softmax + gather. (unchanged)
// ---------------------------------------------------------------------------
__global__ __launch_bounds__(256, 4) void merge_gather_kernel(
    const u32* __restrict__ cand, const f16* __restrict__ values_h,
    f16* __restrict__ mem_out) {
  const int tid = threadIdx.x;
  const int wave = tid >> 6, lane = tid & 63;
  const int rowbase = blockIdx.x * 32 + wave * 8;
  const int myrow = rowbase + (lane & 7);

  const u32* cp = cand + (size_t)myrow * 16;
  u32x4 a0 = *(const u32x4*)(cp);
  u32x4 a1 = *(const u32x4*)(cp + 4);
  u32x4 b0 = *(const u32x4*)(cp + 8);
  u32x4 b1 = *(const u32x4*)(cp + 12);
  u32 top[KTOP] = {a0.x, a0.y, a0.z, a0.w, a1.x, a1.y, a1.z, a1.w};
  u32 ins[KTOP] = {b0.x, b0.y, b0.z, b0.w, b1.x, b1.y, b1.z, b1.w};
#pragma unroll
  for (int j = 0; j < KTOP; ++j) {
    u32 x = ins[j];
#pragma unroll
    for (int jj = 0; jj < KTOP; ++jj) { const u32 nt = umax32(top[jj], x); x = umin32(top[jj], x); top[jj] = nt; }
  }

  float w[KTOP]; u32 idx[KTOP];
  {
    float s[KTOP];
#pragma unroll
    for (int j = 0; j < KTOP; ++j) {
      const u32 mono = top[j] & 0xFFFFF000u;
      const u32 bits = (mono & 0x80000000u) ? (mono ^ 0x80000000u) : ~mono;
      s[j] = __int_as_float(bits);
      idx[j] = top[j] & 0xFFFu;
    }
    const float m0 = s[0];
    float sum = 0.f;
#pragma unroll
    for (int j = 0; j < KTOP; ++j) { w[j] = __expf(s[j] - m0); sum += w[j]; }
    const float inv = 1.f / sum;
#pragma unroll
    for (int j = 0; j < KTOP; ++j) w[j] *= inv;
  }

  for (int r = 0; r < 8; ++r) {
    float acc2[8];
#pragma unroll
    for (int e = 0; e < 8; ++e) acc2[e] = 0.f;
#pragma unroll
    for (int j = 0; j < KTOP; ++j) {
      const u32 ix = (u32)__shfl((int)idx[j], r);
      const float wj = __shfl(w[j], r);
      const f16x8 v = *(const f16x8*)(values_h + (size_t)ix * M_DIM + lane * 8);
#pragma unroll
      for (int e = 0; e < 8; ++e) acc2[e] += wj * (float)v[e];
    }
    f16x8 o;
#pragma unroll
    for (int e = 0; e < 8; ++e) o[e] = (f16)acc2[e];
    *(f16x8*)(mem_out + (size_t)(rowbase + r) * M_DIM + lane * 8) = o;
  }
}

// ---------------------------------------------------------------------------
// outproj (r2 version, proven): row-major LDS + XOR swizzle, coalesced staging.
// ---------------------------------------------------------------------------
__global__ __launch_bounds__(256, 2) void outproj_kernel(
    const f16* __restrict__ mem_h, const f16* __restrict__ woT,
    const float* __restrict__ bo, const float* __restrict__ query,
    float* __restrict__ out) {
  __shared__ f16 Atile[32 * 512];   // 32 KB
  const int tid = threadIdx.x;
  const int wave = tid >> 6, lane = tid & 63;
  const int g = lane >> 4, c = lane & 15;
  const int rowbase = blockIdx.x * 64 + wave * 16;
  const int row = rowbase + c;

  f16x8 Breg[16];
  {
    const f16* mr = mem_h + (size_t)row * M_DIM;
#pragma unroll
    for (int kk = 0; kk < 16; ++kk)
      Breg[kk] = *(const f16x8*)(mr + kk * 32 + g * 8);
  }

  for (int mt = 0; mt < 32; ++mt) {
    __syncthreads();
#pragma unroll
    for (int i2 = 0; i2 < 8; ++i2) {
      const int kr = wave * 8 + i2;
      const u32 kb = ((u32)(lane * 16)) ^ ((u32)((kr & 7) << 4));
      const char* src = (const char*)(woT + (size_t)(mt * 32 + kr) * M_DIM) + kb;
      gload_lds16(src, (char*)Atile + kr * 1024);
    }
    asm volatile("s_waitcnt vmcnt(0)" ::: "memory");
    __syncthreads();

    f32x4 acc0 = {0.f, 0.f, 0.f, 0.f};
    f32x4 acc1 = {0.f, 0.f, 0.f, 0.f};
#pragma unroll
    for (int kk = 0; kk < 16; ++kk) {
      const u32 base = (u32)(kk * 64 + g * 16);
      {
        const int ml = c;
        const u32 off = (u32)(ml * 1024) + (base ^ (u32)((ml & 7) << 4));
        f16x8 a = *(const f16x8*)((const char*)Atile + off);
        acc0 = __builtin_amdgcn_mfma_f32_16x16x32_f16(a, Breg[kk], acc0, 0, 0, 0);
      }
      {
        const int ml = 16 + c;
        const u32 off = (u32)(ml * 1024) + (base ^ (u32)((ml & 7) << 4));
        f16x8 a = *(const f16x8*)((const char*)Atile + off);
        acc1 = __builtin_amdgcn_mfma_f32_16x16x32_f16(a, Breg[kk], acc1, 0, 0, 0);
      }
    }

    const int od0 = mt * 32 + g * 4;
    f32x4 bo0 = *(const f32x4*)(bo + od0);
    f32x4 bo1 = *(const f32x4*)(bo + od0 + 16);
    const float* qp = query + (size_t)row * D_IN + od0;
    f32x4 q0 = *(const f32x4*)(qp);
    f32x4 q1 = *(const f32x4*)(qp + 16);
    f32x4 o0, o1;
#pragma unroll
    for (int i = 0; i < 4; ++i) {
      o0[i] = acc0[i] + bo0[i] + q0[i];
      o1[i] = acc1[i] + bo1[i] + q1[i];
    }
    float* op = out + (size_t)row * D_IN + od0;
    *(f32x4*)(op) = o0;
    *(f32x4*)(op + 16) = o1;
  }
}

extern "C" void kernel_launch(void* const* d_in, const int* in_sizes, int n_in,
                              void* d_out, int out_size, void* d_ws, size_t ws_size,
                              hipStream_t stream) {
  (void)in_sizes; (void)n_in; (void)out_size;
  const float* query = (const float*)d_in[0];
  const float* mkeys = (const float*)d_in[1];
  const float* mvals = (const float*)d_in[2];
  const float* wq    = (const float*)d_in[3];
  const float* bq    = (const float*)d_in[4];
  const float* wo    = (const float*)d_in[5];
  const float* bo    = (const float*)d_in[6];
  float* out = (float*)d_out;

  char* ws = (char*)d_ws;
  f16* keys_h   = (f16*)(ws);                                   //  4 MB
  f16* values_h = (f16*)(ws + (4u << 20));                      //  4 MB
  f16* wqT      = (f16*)(ws + (8u << 20));                      //  1 MB
  f16* woT      = (f16*)(ws + (9u << 20));                      //  1 MB
  f16* q_h      = (f16*)(ws + (10u << 20));                     // 32 MB
  f16* mem_h    = (f16*)(ws + (10u << 20) + (size_t)NROWS * M_DIM * 2);  // 32 MB
  u32* cand     = (u32*)(ws + (10u << 20) + 2ull * (size_t)NROWS * M_DIM * 2); // 2 MB
  const size_t need = (10u << 20) + 2ull * (size_t)NROWS * M_DIM * 2
                    + (size_t)NROWS * 16 * 4;
  if (ws_size < need) return;

  prep_kernel<<<2304, 256, 0, stream>>>(mkeys, mvals, wq, wo, keys_h, values_h, wqT, woT);
  qproj_kernel<<<NROWS / 64, 256, 0, stream>>>(query, wqT, bq, q_h);
  scores_topk_kernel<<<(NROWS / 128) * 2, 512, 0, stream>>>(q_h, keys_h, cand);
  merge_gather_kernel<<<NROWS / 32, 256, 0, stream>>>(cand, values_h, mem_h);
  outproj_kernel<<<NROWS / 64, 256, 0, stream>>>(mem_h, woT, bo, query, out);
}

// Round 9
// 350.704 us; speedup vs baseline: 1.3461x; 1.3461x over previous
//
#include <hip/hip_runtime.h>
#include <cstdint>

typedef _Float16 f16;
typedef uint32_t u32;
typedef f16 f16x2 __attribute__((ext_vector_type(2)));
typedef f16 f16x8 __attribute__((ext_vector_type(8)));
typedef float f32x4 __attribute__((ext_vector_type(4)));
typedef float f32x16 __attribute__((ext_vector_type(16)));
typedef u32 u32x4 __attribute__((ext_vector_type(4)));

#define NROWS 32768   // B*S = 8*4096
#define D_IN 1024
#define M_DIM 512
#define NKEYS 4096
#define KTOP 8

__device__ __forceinline__ u32 umax32(u32 a, u32 b) { return a > b ? a : b; }
__device__ __forceinline__ u32 umin32(u32 a, u32 b) { return a < b ? a : b; }

// async global->LDS, 16B per lane. LDS dest is wave-uniform base + lane*16 (HW).
__device__ __forceinline__ void gload_lds16(const void* src, void* dst) {
  __builtin_amdgcn_global_load_lds(
      (const __attribute__((address_space(1))) uint32_t*)src,
      (__attribute__((address_space(3))) uint32_t*)dst, 16, 0, 0);
}

// ---------------------------------------------------------------------------
// prep: fp32->fp16 conversions + weight transposes (LDS-tiled, coalesced)
// ---------------------------------------------------------------------------
__global__ void prep_kernel(const float* __restrict__ keys, const float* __restrict__ values,
                            const float* __restrict__ wq, const float* __restrict__ wo,
                            f16* __restrict__ keys_h, f16* __restrict__ values_h,
                            f16* __restrict__ wqT, f16* __restrict__ woT) {
  const int b = blockIdx.x, t = threadIdx.x;
  if (b < 2048) {
    const float* src = (b < 1024) ? keys : values;
    f16* dst = (b < 1024) ? keys_h : values_h;
    const int bb = b & 1023;
    const size_t base = (size_t)bb * 2048 + (size_t)t * 8;
    f32x4 a = *(const f32x4*)(src + base);
    f32x4 c2 = *(const f32x4*)(src + base + 4);
    f16x8 o;
    o[0] = (f16)a[0]; o[1] = (f16)a[1]; o[2] = (f16)a[2]; o[3] = (f16)a[3];
    o[4] = (f16)c2[0]; o[5] = (f16)c2[1]; o[6] = (f16)c2[2]; o[7] = (f16)c2[3];
    *(f16x8*)(dst + base) = o;
    return;
  }
  __shared__ float lds[64][65];
  if (b < 2176) {
    // wq: [1024 d][512 m] -> wqT [512 m][1024 d]
    const int tb = b - 2048;           // 0..127
    const int td = tb >> 3, tm = tb & 7;
#pragma unroll
    for (int p = 0; p < 16; ++p) {
      const int d_loc = p * 4 + (t >> 6), m_loc = t & 63;
      lds[d_loc][m_loc] = wq[(size_t)(td * 64 + d_loc) * 512 + tm * 64 + m_loc];
    }
    __syncthreads();
#pragma unroll
    for (int p = 0; p < 16; ++p) {
      const int m_loc = p * 4 + (t >> 6), d_loc = t & 63;
      wqT[(size_t)(tm * 64 + m_loc) * 1024 + td * 64 + d_loc] = (f16)lds[d_loc][m_loc];
    }
  } else {
    // wo: [512 m][1024 od] -> woT [1024 od][512 m]
    const int tb = b - 2176;           // 0..127
    const int tmm = tb >> 4, tod = tb & 15;
#pragma unroll
    for (int p = 0; p < 16; ++p) {
      const int m_loc = p * 4 + (t >> 6), od_loc = t & 63;
      lds[m_loc][od_loc] = wo[(size_t)(tmm * 64 + m_loc) * 1024 + tod * 64 + od_loc];
    }
    __syncthreads();
#pragma unroll
    for (int p = 0; p < 16; ++p) {
      const int od_loc = p * 4 + (t >> 6), m_loc = t & 63;
      woT[(size_t)(tod * 64 + od_loc) * 512 + tmm * 64 + m_loc] = (f16)lds[m_loc][od_loc];
    }
  }
}

// ---------------------------------------------------------------------------
// qproj (r2 version, proven): row-major LDS + XOR swizzle, coalesced staging.
// ---------------------------------------------------------------------------
__global__ __launch_bounds__(256, 2) void qproj_kernel(
    const float* __restrict__ query, const f16* __restrict__ wqT,
    const float* __restrict__ bq, f16* __restrict__ q_out) {
  __shared__ f16 Atile[32 * 1024];   // 64 KB
  const int tid = threadIdx.x;
  const int wave = tid >> 6, lane = tid & 63;
  const int g = lane >> 4, c = lane & 15;
  const int rowbase = blockIdx.x * 64 + wave * 16;
  const int row = rowbase + c;

  f16x8 Breg[32];
  {
    const float* qrow = query + (size_t)row * D_IN;
#pragma unroll
    for (int kk = 0; kk < 32; ++kk) {
      f32x4 lo = *(const f32x4*)(qrow + kk * 32 + g * 8);
      f32x4 hi = *(const f32x4*)(qrow + kk * 32 + g * 8 + 4);
      f16x8 v;
      v[0] = (f16)lo[0]; v[1] = (f16)lo[1]; v[2] = (f16)lo[2]; v[3] = (f16)lo[3];
      v[4] = (f16)hi[0]; v[5] = (f16)hi[1]; v[6] = (f16)hi[2]; v[7] = (f16)hi[3];
      Breg[kk] = v;
    }
  }

  for (int mt = 0; mt < 16; ++mt) {
    __syncthreads();
#pragma unroll
    for (int i2 = 0; i2 < 8; ++i2) {
      const int kr = wave * 8 + i2;
#pragma unroll
      for (int hb = 0; hb < 2; ++hb) {
        const u32 slot = (u32)(hb * 1024 + lane * 16);
        const u32 kb = slot ^ (u32)((kr & 7) << 4);
        const char* src = (const char*)(wqT + (size_t)(mt * 32 + kr) * D_IN) + kb;
        gload_lds16(src, (char*)Atile + kr * 2048 + hb * 1024);
      }
    }
    asm volatile("s_waitcnt vmcnt(0)" ::: "memory");
    __syncthreads();

    f32x4 acc0 = {0.f, 0.f, 0.f, 0.f};
    f32x4 acc1 = {0.f, 0.f, 0.f, 0.f};
#pragma unroll
    for (int kk = 0; kk < 32; ++kk) {
      const u32 base = (u32)(kk * 64 + g * 16);
      {
        const int ml = c;
        const u32 off = (u32)(ml * 2048) + (base ^ (u32)((ml & 7) << 4));
        f16x8 a = *(const f16x8*)((const char*)Atile + off);
        acc0 = __builtin_amdgcn_mfma_f32_16x16x32_f16(a, Breg[kk], acc0, 0, 0, 0);
      }
      {
        const int ml = 16 + c;
        const u32 off = (u32)(ml * 2048) + (base ^ (u32)((ml & 7) << 4));
        f16x8 a = *(const f16x8*)((const char*)Atile + off);
        acc1 = __builtin_amdgcn_mfma_f32_16x16x32_f16(a, Breg[kk], acc1, 0, 0, 0);
      }
    }

    f32x4 bq0 = *(const f32x4*)(bq + mt * 32 + g * 4);
    f32x4 bq1 = *(const f32x4*)(bq + mt * 32 + 16 + g * 4);
    f16* qp = q_out + (size_t)row * M_DIM + mt * 32 + g * 4;
    f16x2 p;
    p[0] = (f16)(acc0[0] + bq0[0]); p[1] = (f16)(acc0[1] + bq0[1]); *(f16x2*)(qp + 0) = p;
    p[0] = (f16)(acc0[2] + bq0[2]); p[1] = (f16)(acc0[3] + bq0[3]); *(f16x2*)(qp + 2) = p;
    p[0] = (f16)(acc1[0] + bq1[0]); p[1] = (f16)(acc1[1] + bq1[1]); *(f16x2*)(qp + 16) = p;
    p[0] = (f16)(acc1[2] + bq1[2]); p[1] = (f16)(acc1[3] + bq1[3]); *(f16x2*)(qp + 18) = p;
  }
}

// ---------------------------------------------------------------------------
// scores+topk over a HALF of the key range (2048 keys), 32x32x16 MFMA,
// r2 structure (lowest LDS traffic) + DEFERRED TOPK: tile t's 16 sums are
// folded into sPrev[16] (16 VGPR) and the pack+insert chain runs inside
// tile t+1's MFMA block — independent dataflow in the same scheduling
// region, so the compiler interleaves the serial VALU chain into the MFMA
// dep-chain bubbles (T15 mechanism). Single top[8] chain (dep latency now
// hidden). Same packed values/set as r2 -> bit-identical output.
// ---------------------------------------------------------------------------
__global__ __launch_bounds__(256, 2) void scores_topk_kernel(
    const f16* __restrict__ q, const f16* __restrict__ keys_h,
    u32* __restrict__ cand) {
  __shared__ f16 Ktile[2][32 * 512];   // 2 x 32 KB
  const int tid = threadIdx.x;
  const int wave = tid >> 6, lane = tid & 63;
  const int h = lane >> 5, r32 = lane & 31;
  const int rb = blockIdx.x >> 1, half = blockIdx.x & 1;
  const int rowbase = rb * 128 + wave * 32;
  const int myrow = rowbase + r32;
  const int keybase = half * 2048;

  f16x8 Breg[32];
  {
    const f16* qr = q + (size_t)myrow * M_DIM;
#pragma unroll
    for (int kk = 0; kk < 32; ++kk)
      Breg[kk] = *(const f16x8*)(qr + kk * 16 + h * 8);
  }

  u32 top[KTOP];
#pragma unroll
  for (int j = 0; j < KTOP; ++j) top[j] = 0u;
  float sPrev[16];

  auto stage = [&](int buf, int kt) {
#pragma unroll
    for (int i2 = 0; i2 < 8; ++i2) {
      const int kr = wave * 8 + i2;
      const u32 kb = ((u32)(lane * 16)) ^ ((u32)((kr & 7) << 4));
      const char* src = (const char*)(keys_h + (size_t)(keybase + kt * 32 + kr) * M_DIM) + kb;
      gload_lds16(src, (char*)&Ktile[buf][0] + kr * 1024);
    }
  };

  // insert the 16 deferred sums of tile (kt-1)
  auto topk_prev = [&](int ktm1) {
#pragma unroll
    for (int i = 0; i < 16; ++i) {
      const u32 kidx = (u32)(keybase + ktm1 * 32 + (i & 3) + 8 * (i >> 2) + 4 * h);
      const int bi = __float_as_int(sPrev[i]);
      const u32 mono = (u32)bi ^ (u32)((bi >> 31) | 0x80000000);   // order-preserving
      u32 x = ((mono + 0x800u) & 0xFFFFF000u) | kidx;              // 20b score + 12b idx
#pragma unroll
      for (int j = 0; j < KTOP; ++j) { const u32 nt = umax32(top[j], x); x = umin32(top[j], x); top[j] = nt; }
    }
  };

  stage(0, 0);
  asm volatile("s_waitcnt vmcnt(0)" ::: "memory");
  __syncthreads();

  const u32 swz = (u32)((r32 & 7) << 4);
  const u32 rowb = (u32)(r32 * 1024);

#pragma unroll 1
  for (int kt = 0; kt < 64; ++kt) {
    const int cur = kt & 1;
    if (kt < 63) stage(cur ^ 1, kt + 1);

    f32x16 accA, accB;
#pragma unroll
    for (int i = 0; i < 16; ++i) { accA[i] = 0.f; accB[i] = 0.f; }
    const char* tileb = (const char*)&Ktile[cur][0];
    __builtin_amdgcn_s_setprio(1);
#pragma unroll
    for (int kk = 0; kk < 32; kk += 2) {
      const u32 offA = rowb + ((u32)(kk * 32 + h * 16) ^ swz);
      const u32 offB = rowb + ((u32)((kk + 1) * 32 + h * 16) ^ swz);
      f16x8 fA = *(const f16x8*)(tileb + offA);
      f16x8 fB = *(const f16x8*)(tileb + offB);
      accA = __builtin_amdgcn_mfma_f32_32x32x16_f16(fA, Breg[kk], accA, 0, 0, 0);
      accB = __builtin_amdgcn_mfma_f32_32x32x16_f16(fB, Breg[kk + 1], accB, 0, 0, 0);
    }
    __builtin_amdgcn_s_setprio(0);

    // previous tile's topk — independent of the MFMA chain above; the
    // scheduler fills MFMA dep bubbles with this serial VALU chain.
    if (kt > 0) topk_prev(kt - 1);

    // fold this tile's sums for next iteration (depends on MFMA results)
#pragma unroll
    for (int i = 0; i < 16; ++i) sPrev[i] = accA[i] + accB[i];

    asm volatile("s_waitcnt vmcnt(0)" ::: "memory");
    __syncthreads();
  }
  topk_prev(63);   // flush last tile

  // merge the two h-halves (disjoint key subsets) -> top-8 of this key half
  u32 oth[KTOP];
#pragma unroll
  for (int j = 0; j < KTOP; ++j) oth[j] = (u32)__shfl((int)top[j], lane ^ 32);
#pragma unroll
  for (int j = 0; j < KTOP; ++j) {
    u32 x = oth[j];
#pragma unroll
    for (int jj = 0; jj < KTOP; ++jj) { const u32 nt = umax32(top[jj], x); x = umin32(top[jj], x); top[jj] = nt; }
  }

  if (h == 0) {
    u32* cp = cand + (size_t)myrow * 16 + half * 8;
    u32x4 a, b;
    a.x = top[0]; a.y = top[1]; a.z = top[2]; a.w = top[3];
    b.x = top[4]; b.y = top[5]; b.z = top[6]; b.w = top[7];
    *(u32x4*)(cp) = a;
    *(u32x4*)(cp + 4) = b;
  }
}

// ---------------------------------------------------------------------------
// merge halves + softmax + gather. (unchanged)
// ---------------------------------------------------------------------------
__global__ __launch_bounds__(256, 4) void merge_gather_kernel(
    const u32* __restrict__ cand, const f16* __restrict__ values_h,
    f16* __restrict__ mem_out) {
  const int tid = threadIdx.x;
  const int wave = tid >> 6, lane = tid & 63;
  const int rowbase = blockIdx.x * 32 + wave * 8;
  const int myrow = rowbase + (lane & 7);

  const u32* cp = cand + (size_t)myrow * 16;
  u32x4 a0 = *(const u32x4*)(cp);
  u32x4 a1 = *(const u32x4*)(cp + 4);
  u32x4 b0 = *(const u32x4*)(cp + 8);
  u32x4 b1 = *(const u32x4*)(cp + 12);
  u32 top[KTOP] = {a0.x, a0.y, a0.z, a0.w, a1.x, a1.y, a1.z, a1.w};
  u32 ins[KTOP] = {b0.x, b0.y, b0.z, b0.w, b1.x, b1.y, b1.z, b1.w};
#pragma unroll
  for (int j = 0; j < KTOP; ++j) {
    u32 x = ins[j];
#pragma unroll
    for (int jj = 0; jj < KTOP; ++jj) { const u32 nt = umax32(top[jj], x); x = umin32(top[jj], x); top[jj] = nt; }
  }

  float w[KTOP]; u32 idx[KTOP];
  {
    float s[KTOP];
#pragma unroll
    for (int j = 0; j < KTOP; ++j) {
      const u32 mono = top[j] & 0xFFFFF000u;
      const u32 bits = (mono & 0x80000000u) ? (mono ^ 0x80000000u) : ~mono;
      s[j] = __int_as_float(bits);
      idx[j] = top[j] & 0xFFFu;
    }
    const float m0 = s[0];
    float sum = 0.f;
#pragma unroll
    for (int j = 0; j < KTOP; ++j) { w[j] = __expf(s[j] - m0); sum += w[j]; }
    const float inv = 1.f / sum;
#pragma unroll
    for (int j = 0; j < KTOP; ++j) w[j] *= inv;
  }

  for (int r = 0; r < 8; ++r) {
    float acc2[8];
#pragma unroll
    for (int e = 0; e < 8; ++e) acc2[e] = 0.f;
#pragma unroll
    for (int j = 0; j < KTOP; ++j) {
      const u32 ix = (u32)__shfl((int)idx[j], r);
      const float wj = __shfl(w[j], r);
      const f16x8 v = *(const f16x8*)(values_h + (size_t)ix * M_DIM + lane * 8);
#pragma unroll
      for (int e = 0; e < 8; ++e) acc2[e] += wj * (float)v[e];
    }
    f16x8 o;
#pragma unroll
    for (int e = 0; e < 8; ++e) o[e] = (f16)acc2[e];
    *(f16x8*)(mem_out + (size_t)(rowbase + r) * M_DIM + lane * 8) = o;
  }
}

// ---------------------------------------------------------------------------
// outproj (r2 math) with OCCUPANCY FIX: mt-loop split across grid
// (blockIdx = rbk*2 + mh, mh covers od [mh*512, +512)) -> grid 1024 =
// 4 blocks/CU; VGPR ~100 -> 4 waves/SIMD (was 2).
// ---------------------------------------------------------------------------
__global__ __launch_bounds__(256, 4) void outproj_kernel(
    const f16* __restrict__ mem_h, const f16* __restrict__ woT,
    const float* __restrict__ bo, const float* __restrict__ query,
    float* __restrict__ out) {
  __shared__ f16 Atile[32 * 512];   // 32 KB
  const int tid = threadIdx.x;
  const int wave = tid >> 6, lane = tid & 63;
  const int g = lane >> 4, c = lane & 15;
  const int rbk = blockIdx.x >> 1, mh = blockIdx.x & 1;
  const int rowbase = rbk * 64 + wave * 16;
  const int row = rowbase + c;

  f16x8 Breg[16];
  {
    const f16* mr = mem_h + (size_t)row * M_DIM;
#pragma unroll
    for (int kk = 0; kk < 16; ++kk)
      Breg[kk] = *(const f16x8*)(mr + kk * 32 + g * 8);
  }

  for (int mt = mh * 16; mt < mh * 16 + 16; ++mt) {
    __syncthreads();
#pragma unroll
    for (int i2 = 0; i2 < 8; ++i2) {
      const int kr = wave * 8 + i2;
      const u32 kb = ((u32)(lane * 16)) ^ ((u32)((kr & 7) << 4));
      const char* src = (const char*)(woT + (size_t)(mt * 32 + kr) * M_DIM) + kb;
      gload_lds16(src, (char*)Atile + kr * 1024);
    }
    asm volatile("s_waitcnt vmcnt(0)" ::: "memory");
    __syncthreads();

    f32x4 acc0 = {0.f, 0.f, 0.f, 0.f};
    f32x4 acc1 = {0.f, 0.f, 0.f, 0.f};
#pragma unroll
    for (int kk = 0; kk < 16; ++kk) {
      const u32 base = (u32)(kk * 64 + g * 16);
      {
        const int ml = c;
        const u32 off = (u32)(ml * 1024) + (base ^ (u32)((ml & 7) << 4));
        f16x8 a = *(const f16x8*)((const char*)Atile + off);
        acc0 = __builtin_amdgcn_mfma_f32_16x16x32_f16(a, Breg[kk], acc0, 0, 0, 0);
      }
      {
        const int ml = 16 + c;
        const u32 off = (u32)(ml * 1024) + (base ^ (u32)((ml & 7) << 4));
        f16x8 a = *(const f16x8*)((const char*)Atile + off);
        acc1 = __builtin_amdgcn_mfma_f32_16x16x32_f16(a, Breg[kk], acc1, 0, 0, 0);
      }
    }

    const int od0 = mt * 32 + g * 4;
    f32x4 bo0 = *(const f32x4*)(bo + od0);
    f32x4 bo1 = *(const f32x4*)(bo + od0 + 16);
    const float* qp = query + (size_t)row * D_IN + od0;
    f32x4 q0 = *(const f32x4*)(qp);
    f32x4 q1 = *(const f32x4*)(qp + 16);
    f32x4 o0, o1;
#pragma unroll
    for (int i = 0; i < 4; ++i) {
      o0[i] = acc0[i] + bo0[i] + q0[i];
      o1[i] = acc1[i] + bo1[i] + q1[i];
    }
    float* op = out + (size_t)row * D_IN + od0;
    *(f32x4*)(op) = o0;
    *(f32x4*)(op + 16) = o1;
  }
}

extern "C" void kernel_launch(void* const* d_in, const int* in_sizes, int n_in,
                              void* d_out, int out_size, void* d_ws, size_t ws_size,
                              hipStream_t stream) {
  (void)in_sizes; (void)n_in; (void)out_size;
  const float* query = (const float*)d_in[0];
  const float* mkeys = (const float*)d_in[1];
  const float* mvals = (const float*)d_in[2];
  const float* wq    = (const float*)d_in[3];
  const float* bq    = (const float*)d_in[4];
  const float* wo    = (const float*)d_in[5];
  const float* bo    = (const float*)d_in[6];
  float* out = (float*)d_out;

  char* ws = (char*)d_ws;
  f16* keys_h   = (f16*)(ws);                                   //  4 MB
  f16* values_h = (f16*)(ws + (4u << 20));                      //  4 MB
  f16* wqT      = (f16*)(ws + (8u << 20));                      //  1 MB
  f16* woT      = (f16*)(ws + (9u << 20));                      //  1 MB
  f16* q_h      = (f16*)(ws + (10u << 20));                     // 32 MB
  f16* mem_h    = (f16*)(ws + (10u << 20) + (size_t)NROWS * M_DIM * 2);  // 32 MB
  u32* cand     = (u32*)(ws + (10u << 20) + 2ull * (size_t)NROWS * M_DIM * 2); // 2 MB
  const size_t need = (10u << 20) + 2ull * (size_t)NROWS * M_DIM * 2
                    + (size_t)NROWS * 16 * 4;
  if (ws_size < need) return;

  prep_kernel<<<2304, 256, 0, stream>>>(mkeys, mvals, wq, wo, keys_h, values_h, wqT, woT);
  qproj_kernel<<<NROWS / 64, 256, 0, stream>>>(query, wqT, bq, q_h);
  scores_topk_kernel<<<(NROWS / 128) * 2, 256, 0, stream>>>(q_h, keys_h, cand);
  merge_gather_kernel<<<NROWS / 32, 256, 0, stream>>>(cand, values_h, mem_h);
  outproj_kernel<<<(NROWS / 64) * 2, 256, 0, stream>>>(mem_h, woT, bo, query, out);
}